// Round 2
// baseline (180.466 us; speedup 1.0000x reference)
//
#include <hip/hip_runtime.h>
#include <hip/hip_bf16.h>
#include <math.h>

#define II 1024
#define HH 1024
#define LL 16384
#define EPSF 1e-8f

__device__ __forceinline__ float wave_reduce_sum(float v) {
    #pragma unroll
    for (int off = 32; off; off >>= 1) v += __shfl_down(v, off);
    return v;
}

// ---- K1: fused q-matvec (rows 0..1023) + gh-matvec (rows 1024..4095) -------
// q[r]  = attn_w[r,:] . [emb_row | h0] + attn_b[r]
// gh[r] = w_hh[r,:] . h0 + b_hh[r]
__global__ void qgh_kernel(const int* __restrict__ token,
                           const float* __restrict__ emb,
                           const float* __restrict__ hidden,
                           const float* __restrict__ attn_w,
                           const float* __restrict__ attn_b,
                           const float* __restrict__ w_hh,
                           const float* __restrict__ b_hh,
                           float* __restrict__ q, float* __restrict__ gh) {
    int w = (blockIdx.x * blockDim.x + threadIdx.x) >> 6;
    int lane = threadIdx.x & 63;
    if (w < HH) {
        const float* er = emb + (size_t)token[0] * II;
        const float* row = attn_w + (size_t)w * (II + HH);
        float acc = 0.f;
        for (int k = lane * 4; k < II + HH; k += 256) {
            float4 wv = *reinterpret_cast<const float4*>(row + k);
            const float* src = (k < II) ? (er + k) : (hidden + (k - II));
            float4 xv = *reinterpret_cast<const float4*>(src);
            acc += wv.x * xv.x + wv.y * xv.y + wv.z * xv.z + wv.w * xv.w;
        }
        acc = wave_reduce_sum(acc);
        if (lane == 0) q[w] = acc + attn_b[w];
    } else {
        int r = w - HH;  // 0..3071
        const float* row = w_hh + (size_t)r * HH;
        float acc = 0.f;
        for (int k = lane * 4; k < HH; k += 256) {
            float4 wv = *reinterpret_cast<const float4*>(row + k);
            float4 xv = *reinterpret_cast<const float4*>(hidden + k);
            acc += wv.x * xv.x + wv.y * xv.y + wv.z * xv.z + wv.w * xv.w;
        }
        acc = wave_reduce_sum(acc);
        if (lane == 0) gh[r] = acc + b_hh[r];
    }
}

// ---- K2: dot[l] = enc[l].q ; en[l] = max(||enc[l]||, eps) ------------------
__global__ void doten_kernel(const float* __restrict__ enc,
                             const float* __restrict__ q,
                             float* __restrict__ dot_out,
                             float* __restrict__ en_out) {
    int w = (blockIdx.x * blockDim.x + threadIdx.x) >> 6;
    int lane = threadIdx.x & 63;
    if (w >= LL) return;
    const float* row = enc + (size_t)w * HH;
    float dot = 0.f, ss = 0.f;
    for (int k = lane * 4; k < HH; k += 256) {
        float4 e = *reinterpret_cast<const float4*>(row + k);
        float4 qv = *reinterpret_cast<const float4*>(q + k);
        dot += e.x * qv.x + e.y * qv.y + e.z * qv.z + e.w * qv.w;
        ss  += e.x * e.x + e.y * e.y + e.z * e.z + e.w * e.w;
    }
    #pragma unroll
    for (int off = 32; off; off >>= 1) {
        dot += __shfl_down(dot, off);
        ss  += __shfl_down(ss, off);
    }
    if (lane == 0) {
        dot_out[w] = dot;
        en_out[w] = fmaxf(sqrtf(ss), EPSF);
    }
}

// ---- K3: qn + softmax -> normalized weights (single block, 256 thr) --------
__global__ void softmax_kernel(const float* __restrict__ q,
                               const float* __restrict__ dot,
                               const float* __restrict__ en,
                               float* __restrict__ w_out,
                               float* __restrict__ sims_tmp) {
    __shared__ float red[4];
    __shared__ float sh;
    int tid = threadIdx.x, wave = tid >> 6, lane = tid & 63;
    // qn = max(||q||, eps)
    float ss = 0.f;
    for (int i = tid; i < HH; i += 256) ss += q[i] * q[i];
    ss = wave_reduce_sum(ss);
    if (lane == 0) red[wave] = ss;
    __syncthreads();
    if (tid == 0) sh = fmaxf(sqrtf(red[0] + red[1] + red[2] + red[3]), EPSF);
    __syncthreads();
    float qn = sh;
    __syncthreads();
    // pass 1: sims + max
    float m = -INFINITY;
    for (int i = tid; i < LL; i += 256) {
        float s = dot[i] / (qn * en[i]);
        sims_tmp[i] = s;
        m = fmaxf(m, s);
    }
    #pragma unroll
    for (int off = 32; off; off >>= 1) m = fmaxf(m, __shfl_down(m, off));
    if (lane == 0) red[wave] = m;
    __syncthreads();
    if (tid == 0)
        sh = fmaxf(fmaxf(red[0], red[1]), fmaxf(red[2], red[3]));
    __syncthreads();
    m = sh;
    __syncthreads();
    // pass 2: sum of exp
    float s = 0.f;
    for (int i = tid; i < LL; i += 256) s += expf(sims_tmp[i] - m);
    s = wave_reduce_sum(s);
    if (lane == 0) red[wave] = s;
    __syncthreads();
    if (tid == 0) sh = red[0] + red[1] + red[2] + red[3];
    __syncthreads();
    float inv = 1.f / sh;
    // pass 3: write normalized weights
    for (int i = tid; i < LL; i += 256)
        w_out[i] = expf(sims_tmp[i] - m) * inv;
}

// ---- K4: colsum partials. block b: rows [b*rpc, (b+1)*rpc), all 1024 cols --
__global__ void colsum_kernel(const float* __restrict__ enc,
                              const float* __restrict__ w,
                              float* __restrict__ partial, int rowsPerChunk) {
    int tid = threadIdx.x;            // 0..255, col4 = tid
    int r0 = blockIdx.x * rowsPerChunk;
    const float4* enc4 = reinterpret_cast<const float4*>(enc);
    float4 acc = {0.f, 0.f, 0.f, 0.f};
    for (int r = r0; r < r0 + rowsPerChunk; ++r) {
        float wv = w[r];
        float4 e = enc4[(size_t)r * 256 + tid];
        acc.x = fmaf(wv, e.x, acc.x);
        acc.y = fmaf(wv, e.y, acc.y);
        acc.z = fmaf(wv, e.z, acc.z);
        acc.w = fmaf(wv, e.w, acc.w);
    }
    reinterpret_cast<float4*>(partial)[(size_t)blockIdx.x * 256 + tid] = acc;
}

// ---- K5: reduce partials -> attn_applied -----------------------------------
__global__ void reduce_partials_kernel(const float* __restrict__ partial,
                                       float* __restrict__ out, int nChunks) {
    int c = blockIdx.x * blockDim.x + threadIdx.x;
    if (c >= HH) return;
    float acc = 0.f;
    for (int i = 0; i < nChunks; ++i) acc += partial[(size_t)i * HH + c];
    out[c] = acc;
}

// ---- K6: x = relu(comb_w . [emb_row | attn_applied] + comb_b) --------------
__global__ void xmatvec_kernel(const int* __restrict__ token,
                               const float* __restrict__ emb,
                               const float* __restrict__ aa,
                               const float* __restrict__ comb_w,
                               const float* __restrict__ comb_b,
                               float* __restrict__ x) {
    int w = (blockIdx.x * blockDim.x + threadIdx.x) >> 6;
    int lane = threadIdx.x & 63;
    if (w >= II) return;
    const float* er = emb + (size_t)token[0] * II;
    const float* row = comb_w + (size_t)w * (II + HH);
    float acc = 0.f;
    for (int k = lane * 4; k < II + HH; k += 256) {
        float4 wv = *reinterpret_cast<const float4*>(row + k);
        const float* src = (k < II) ? (er + k) : (aa + (k - II));
        float4 xv = *reinterpret_cast<const float4*>(src);
        acc += wv.x * xv.x + wv.y * xv.y + wv.z * xv.z + wv.w * xv.w;
    }
    acc = wave_reduce_sum(acc);
    if (lane == 0) x[w] = fmaxf(acc + comb_b[w], 0.f);
}

// ---- K7: gi = w_ih . x + b_ih (3072 rows) ----------------------------------
__global__ void gi_kernel(const float* __restrict__ w_ih,
                          const float* __restrict__ x,
                          const float* __restrict__ b_ih,
                          float* __restrict__ gi) {
    int w = (blockIdx.x * blockDim.x + threadIdx.x) >> 6;
    int lane = threadIdx.x & 63;
    if (w >= 3 * HH) return;
    const float* row = w_ih + (size_t)w * II;
    float acc = 0.f;
    for (int k = lane * 4; k < II; k += 256) {
        float4 wv = *reinterpret_cast<const float4*>(row + k);
        float4 xv = *reinterpret_cast<const float4*>(x + k);
        acc += wv.x * xv.x + wv.y * xv.y + wv.z * xv.z + wv.w * xv.w;
    }
    acc = wave_reduce_sum(acc);
    if (lane == 0) gi[w] = acc + b_ih[w];
}

// ---- K8: GRU gates + fc2/relu head + out scalar (single block, 256 thr) ----
__global__ void gruhead_kernel(const float* __restrict__ gi,
                               const float* __restrict__ gh,
                               const float* __restrict__ h0,
                               const float* __restrict__ fc2_w,
                               const float* __restrict__ fc2_b,
                               const float* __restrict__ out_w,
                               const float* __restrict__ out_b,
                               float* __restrict__ h_new_out,
                               float* __restrict__ out_scalar) {
    __shared__ float hsh[HH];
    __shared__ float f[64];
    int tid = threadIdx.x, wave = tid >> 6, lane = tid & 63;
    for (int i = tid; i < HH; i += 256) {
        float r = 1.f / (1.f + expf(-(gi[i] + gh[i])));
        float z = 1.f / (1.f + expf(-(gi[HH + i] + gh[HH + i])));
        float nn = tanhf(gi[2 * HH + i] + r * gh[2 * HH + i]);
        float h = (1.f - z) * nn + z * h0[i];
        h_new_out[i] = h;
        hsh[i] = h;
    }
    __syncthreads();
    // fc2: 64 rows over 4 waves (16 rows each)
    for (int rr = 0; rr < 16; ++rr) {
        int r = wave * 16 + rr;
        const float* row = fc2_w + (size_t)r * HH;
        float acc = 0.f;
        for (int k = lane * 4; k < HH; k += 256) {
            float4 wv = *reinterpret_cast<const float4*>(row + k);
            acc += wv.x * hsh[k] + wv.y * hsh[k + 1] + wv.z * hsh[k + 2] +
                   wv.w * hsh[k + 3];
        }
        acc = wave_reduce_sum(acc);
        if (lane == 0) f[r] = fmaxf(acc + fc2_b[r], 0.f);
    }
    __syncthreads();
    if (tid < 64) {
        float v = f[tid] * out_w[tid];
        v = wave_reduce_sum(v);
        if (tid == 0) out_scalar[0] = v + out_b[0];
    }
}

extern "C" void kernel_launch(void* const* d_in, const int* in_sizes, int n_in,
                              void* d_out, int out_size, void* d_ws,
                              size_t ws_size, hipStream_t stream) {
    const int*   token = (const int*)d_in[0];
    const float* hidden = (const float*)d_in[1];
    const float* enc = (const float*)d_in[2];
    const float* emb = (const float*)d_in[3];
    const float* attn_w = (const float*)d_in[4];
    const float* attn_b = (const float*)d_in[5];
    const float* comb_w = (const float*)d_in[6];
    const float* comb_b = (const float*)d_in[7];
    const float* w_ih = (const float*)d_in[8];
    const float* w_hh = (const float*)d_in[9];
    const float* b_ih = (const float*)d_in[10];
    const float* b_hh = (const float*)d_in[11];
    const float* fc2_w = (const float*)d_in[12];
    const float* fc2_b = (const float*)d_in[13];
    const float* out_w = (const float*)d_in[14];
    const float* out_b = (const float*)d_in[15];

    float* ws = (float*)d_ws;
    float* q    = ws + 0;       // 1024
    float* x    = ws + 1024;    // 1024
    float* aa   = ws + 2048;    // 1024 (attn_applied)
    float* gi   = ws + 3072;    // 3072
    float* gh   = ws + 6144;    // 3072
    float* dot  = ws + 16384;   // 16384
    float* en   = ws + 32768;   // 16384
    float* part = ws + 49152;   // nChunks*1024  (also reused as sims_tmp)

    int nChunks = 256;
    while (nChunks > 8 && (size_t)(49152 + nChunks * 1024) * 4 > ws_size)
        nChunks >>= 1;
    int rowsPerChunk = LL / nChunks;

    float* out_scalar = (float*)d_out;             // [0]
    float* h_new = (float*)d_out + 1;              // [1..1024]
    float* attn_weights = (float*)d_out + 1 + HH;  // [1025..17408]

    // K1: q + gh (4096 waves)
    qgh_kernel<<<1024, 256, 0, stream>>>(token, emb, hidden, attn_w, attn_b,
                                         w_hh, b_hh, q, gh);
    // K2: dot/en over enc (64 MB read)
    doten_kernel<<<4096, 256, 0, stream>>>(enc, q, dot, en);
    // K3: qn + softmax -> attn_weights (sims_tmp scratch = part area)
    softmax_kernel<<<1, 256, 0, stream>>>(q, dot, en, attn_weights, part);
    // K4: weighted colsum partials (second enc pass, L3-hot)
    colsum_kernel<<<nChunks, 256, 0, stream>>>(enc, attn_weights, part,
                                               rowsPerChunk);
    // K5: reduce -> attn_applied
    reduce_partials_kernel<<<4, 256, 0, stream>>>(part, aa, nChunks);
    // K6: x = relu(comb .)
    xmatvec_kernel<<<256, 256, 0, stream>>>(token, emb, aa, comb_w, comb_b, x);
    // K7: gi
    gi_kernel<<<768, 256, 0, stream>>>(w_ih, x, b_ih, gi);
    // K8: gru + head
    gruhead_kernel<<<1, 256, 0, stream>>>(gi, gh, hidden, fc2_w, fc2_b, out_w,
                                          out_b, h_new, out_scalar);
}